// Round 6
// baseline (1436.376 us; speedup 1.0000x reference)
//
#include <hip/hip_runtime.h>
#include <hip/hip_bf16.h>

// ---------------- problem constants ----------------
#define T_TOK 8192          // B*S tokens
#define D_DIM 1024
#define F_DIM 2048
#define E_NUM 8
#define NPAIR (T_TOK*2)     // 16384 token-expert pairs (top-2)
#define BM 64               // row tile (pairs)
#define MAX_TILES (NPAIR/BM + E_NUM)   // 264 >= sum_e ceil(n_e/64)
#define LDA 72              // padded LDS row stride (bf16 elems)

// ---------------- compact ws layout (bytes) ----------------
// meta ints: [0..7]=counts, [8..15]=cursors, [16..24]=seg offsets, [25]=ntiles, [26]=f32flag
#define META_OFF   0ULL          // 4 KB (zeroed by k_zero)
#define TILE_OFF   4096ULL       // int4 * 264
#define RIDX_OFF   12288ULL      // int  [T*2]
#define RW_OFF     77824ULL      // f32  [T*2]
#define PT_OFF     143360ULL     // int  [NPAIR]
#define PW_OFF     208896ULL     // f32  [NPAIR]
#define H_OFF      524288ULL     // bf16 [(NPAIR/NC + 64) * F]
#define MIN_WS     (H_OFF + (size_t)(NPAIR/256 + 64) * F_DIM * 2)   // 1,048,576

typedef __bf16 bf16_8 __attribute__((ext_vector_type(8)));
typedef float  f32_4  __attribute__((ext_vector_type(4)));

__device__ __forceinline__ float bf2f(unsigned short u) {
    union { unsigned u32; float f; } v; v.u32 = ((unsigned)u) << 16; return v.f;
}
__device__ __forceinline__ unsigned short f2bf(float f) {
    union { float f; unsigned u; } v; v.f = f;
    unsigned u = v.u;
    unsigned r = (u + 0x7FFFu + ((u >> 16) & 1u)) >> 16;   // RNE
    return (unsigned short)r;
}
__device__ __forceinline__ int iclamp(int v, int lo, int hi) {
    return v < lo ? lo : (v > hi ? hi : v);
}
// load 8 consecutive elements (element index ei, multiple of 8) as 8 packed bf16
__device__ __forceinline__ uint4 load8(const void* base, size_t ei, int f32) {
    if (f32) {
        const float* p = (const float*)base + ei;
        uint4 a = *(const uint4*)p;
        uint4 b = *(const uint4*)(p + 4);
        const float* fa = (const float*)&a;
        const float* fb = (const float*)&b;
        uint4 r;
        unsigned short* s = (unsigned short*)&r;
#pragma unroll
        for (int j = 0; j < 4; j++) { s[j] = f2bf(fa[j]); s[4+j] = f2bf(fb[j]); }
        return r;
    }
    return *(const uint4*)((const unsigned short*)base + ei);
}
__device__ __forceinline__ float loadf(const void* base, size_t ei, int f32) {
    return f32 ? ((const float*)base)[ei] : bf2f(((const unsigned short*)base)[ei]);
}
// load 8 consecutive elements as FULL-PRECISION f32 (router path — no bf16 rounding)
__device__ __forceinline__ void load8f(const void* base, size_t ei, int f32, float* o) {
    if (f32) {
        const float* p = (const float*)base + ei;
        uint4 a = *(const uint4*)p;
        uint4 b = *(const uint4*)(p + 4);
        const float* fa = (const float*)&a;
        const float* fb = (const float*)&b;
#pragma unroll
        for (int j = 0; j < 4; j++) { o[j] = fa[j]; o[4+j] = fb[j]; }
    } else {
        uint4 r = *(const uint4*)((const unsigned short*)base + ei);
        const unsigned short* s = (const unsigned short*)&r;
#pragma unroll
        for (int j = 0; j < 8; j++) o[j] = bf2f(s[j]);
    }
}

// ---------------- zero meta ----------------
__global__ void k_zero(int* __restrict__ p)
{
    p[blockIdx.x * 256 + threadIdx.x] = 0;    // <<<4,256>>>
}

// ---------------- zero output (f32, accumulated via atomicAdd) ----------------
__global__ __launch_bounds__(256) void k_zero_out(uint4* __restrict__ p)
{
    p[(size_t)blockIdx.x * 256 + threadIdx.x] = make_uint4(0,0,0,0);  // <<<8192,256>>> = 32 MB
}

// ---------------- dtype detect: meta[26] = 1 if inputs are float32 ----------------
__global__ void k_dtype(const unsigned* __restrict__ x, int* __restrict__ meta)
{
    if (threadIdx.x == 0 && blockIdx.x == 0) {
        int cnt = 0;
        for (int i = 0; i < 64; i++) {
            unsigned w = x[i];
            int e = (int)((w >> 7) & 0xffu);
            cnt += (e >= 118 && e <= 136) ? 1 : 0;
        }
        meta[26] = (cnt < 32) ? 1 : 0;
    }
}

// ---------------- router (full f32 precision) ----------------
__global__ __launch_bounds__(256) void k_router(const void* __restrict__ x,
                                                const void* __restrict__ wg,
                                                int* __restrict__ meta,
                                                int* __restrict__ ridx,
                                                float* __restrict__ rw)
{
    int lane = threadIdx.x & 63;
    int wv   = threadIdx.x >> 6;
    int t    = blockIdx.x * 4 + wv;        // one wave per token, grid exact
    int fl   = meta[26];
    float acc[E_NUM];
#pragma unroll
    for (int e = 0; e < E_NUM; e++) acc[e] = 0.f;
    for (int d = lane; d < D_DIM; d += 64) {
        float xv = loadf(x, (size_t)t * D_DIM + d, fl);
        float wr[E_NUM];
        load8f(wg, (size_t)d * E_NUM, fl, wr);
#pragma unroll
        for (int e = 0; e < E_NUM; e++) acc[e] += xv * wr[e];
    }
#pragma unroll
    for (int off = 32; off > 0; off >>= 1)
#pragma unroll
        for (int e = 0; e < E_NUM; e++) acc[e] += __shfl_xor(acc[e], off, 64);

    if (lane == 0) {
        int i0 = 0; float m0v = acc[0];
        for (int e = 1; e < E_NUM; e++) if (acc[e] > m0v) { m0v = acc[e]; i0 = e; }
        int i1 = (i0 == 0) ? 1 : 0; float m1v = acc[i1];
        for (int e = 0; e < E_NUM; e++) if (e != i0 && acc[e] > m1v) { m1v = acc[e]; i1 = e; }
        float e1 = __expf(m1v - m0v);
        float w0 = 1.f / (1.f + e1);
        ridx[2*t] = i0; ridx[2*t+1] = i1;
        rw[2*t] = w0;   rw[2*t+1] = 1.f - w0;
        atomicAdd(&meta[i0], 1);
        atomicAdd(&meta[i1], 1);
    }
}

// ---------------- setup ----------------
__global__ void k_setup(int* __restrict__ meta, int4* __restrict__ tiles)
{
    if (threadIdx.x == 0 && blockIdx.x == 0) {
        int seg = 0, nt = 0;
        for (int e = 0; e < E_NUM; e++) {
            int c = meta[e]; c = iclamp(c, 0, NPAIR);
            meta[16 + e] = seg;
            meta[8 + e]  = seg;
            for (int m0 = 0; m0 < c && nt < MAX_TILES; m0 += BM) {
                int r = c - m0; if (r > BM) r = BM;
                tiles[nt++] = make_int4(seg + m0, e, r, 0);
            }
            seg += c;
        }
        meta[24] = seg;
        meta[25] = nt;
    }
}

// ---------------- scatter ----------------
__global__ __launch_bounds__(256) void k_scatter(const int* __restrict__ ridx,
                                                 const float* __restrict__ rw,
                                                 int* __restrict__ meta,
                                                 int* __restrict__ pt,
                                                 float* __restrict__ pw)
{
    __shared__ int lh[E_NUM];
    __shared__ int lbase[E_NUM];
    int tid = threadIdx.x;
    if (tid < E_NUM) lh[tid] = 0;
    __syncthreads();
    int t  = blockIdx.x * 256 + tid;
    int e0 = iclamp(ridx[2*t], 0, E_NUM-1);
    int e1 = iclamp(ridx[2*t+1], 0, E_NUM-1);
    int p0 = atomicAdd(&lh[e0], 1);
    int p1 = atomicAdd(&lh[e1], 1);
    __syncthreads();
    if (tid < E_NUM) lbase[tid] = atomicAdd(&meta[8 + tid], lh[tid]);
    __syncthreads();
    int pos0 = iclamp(lbase[e0] + p0, 0, NPAIR-1);
    int pos1 = iclamp(lbase[e1] + p1, 0, NPAIR-1);
    pt[pos0] = t; pw[pos0] = rw[2*t];
    pt[pos1] = t; pw[pos1] = rw[2*t+1];
}

// ---------------- GEMM1: H = silu(X*W1) .* (X*W3) ----------------
__global__ __launch_bounds__(256) void k_gemm1(const void* __restrict__ x,
                                               const void* __restrict__ w1,
                                               const void* __restrict__ w3,
                                               const int*  __restrict__ meta,
                                               const int4* __restrict__ tiles,
                                               const int*  __restrict__ pt,
                                               unsigned short* __restrict__ H,
                                               int cbase, int clen)
{
    __shared__ unsigned short As [64 * LDA];
    __shared__ unsigned short B1s[64 * LDA];
    __shared__ unsigned short B3s[64 * LDA];
    int nt = iclamp(meta[25], 0, MAX_TILES);
    if ((int)blockIdx.x >= nt) return;
    int4 td = tiles[blockIdx.x];
    if (td.x < cbase || td.x >= cbase + clen) return;
    int fl   = meta[26];
    int base = iclamp(td.x, 0, NPAIR-1);
    int e    = iclamp(td.y, 0, E_NUM-1);
    int rows = iclamp(td.z, 1, BM);
    if (base + rows > NPAIR) rows = NPAIR - base;
    int hrows = clen + 64;
    int lbase_r = base - cbase;
    int f0 = blockIdx.y * 64;
    int tid = threadIdx.x, lane = tid & 63, wv = tid >> 6;

    int arow = tid >> 2;
    int acol = (tid & 3) * 16;
    int ar   = arow < rows ? arow : rows - 1;
    int atok = iclamp(pt[base + ar], 0, T_TOK-1);
    size_t abase = (size_t)atok * D_DIM + acol;

    int bu  = tid & 127;
    int bd0 = (bu & 15) * 4;
    int bf0 = (bu >> 4) * 8;
    const void* bsrc = (tid < 128) ? w1 : w3;
    size_t bb = (size_t)e * D_DIM * F_DIM + (size_t)f0 + bf0;   // + (bd0+k0+i)*F
    unsigned short* bdst = (tid < 128 ? B1s : B3s);

    f32_4 acc1[4], acc3[4];
#pragma unroll
    for (int nn = 0; nn < 4; nn++) { acc1[nn] = 0.f; acc3[nn] = 0.f; }

    for (int k0 = 0; k0 < D_DIM; k0 += 64) {
        uint4 av0 = load8(x, abase + k0, fl);
        uint4 av1 = load8(x, abase + k0 + 8, fl);
        uint4 r0 = load8(bsrc, bb + (size_t)(bd0 + k0 + 0) * F_DIM, fl);
        uint4 r1 = load8(bsrc, bb + (size_t)(bd0 + k0 + 1) * F_DIM, fl);
        uint4 r2 = load8(bsrc, bb + (size_t)(bd0 + k0 + 2) * F_DIM, fl);
        uint4 r3 = load8(bsrc, bb + (size_t)(bd0 + k0 + 3) * F_DIM, fl);
        *(uint4*)&As[arow * LDA + acol]     = av0;
        *(uint4*)&As[arow * LDA + acol + 8] = av1;
        const unsigned short* s0 = (const unsigned short*)&r0;
        const unsigned short* s1 = (const unsigned short*)&r1;
        const unsigned short* s2 = (const unsigned short*)&r2;
        const unsigned short* s3 = (const unsigned short*)&r3;
#pragma unroll
        for (int j = 0; j < 8; j++) {
            uint2 pk;
            pk.x = (unsigned)s0[j] | ((unsigned)s1[j] << 16);
            pk.y = (unsigned)s2[j] | ((unsigned)s3[j] << 16);
            *(uint2*)&bdst[(bf0 + j) * LDA + bd0] = pk;   // transposed: [f][d]
        }
        __syncthreads();
#pragma unroll
        for (int kk = 0; kk < 2; kk++) {
            int ko = kk * 32 + (lane >> 4) * 8;
            bf16_8 a = *(const bf16_8*)&As[(wv * 16 + (lane & 15)) * LDA + ko];
#pragma unroll
            for (int nn = 0; nn < 4; nn++) {
                bf16_8 b1 = *(const bf16_8*)&B1s[(nn * 16 + (lane & 15)) * LDA + ko];
                acc1[nn] = __builtin_amdgcn_mfma_f32_16x16x32_bf16(a, b1, acc1[nn], 0, 0, 0);
                bf16_8 b3 = *(const bf16_8*)&B3s[(nn * 16 + (lane & 15)) * LDA + ko];
                acc3[nn] = __builtin_amdgcn_mfma_f32_16x16x32_bf16(a, b3, acc3[nn], 0, 0, 0);
            }
        }
        __syncthreads();
    }
#pragma unroll
    for (int reg = 0; reg < 4; reg++) {
        int r = wv * 16 + (lane >> 4) * 4 + reg;
        if (r < rows) {
            int hr = iclamp(lbase_r + r, 0, hrows - 1);
            size_t rowoff = (size_t)hr * F_DIM + f0;
#pragma unroll
            for (int nn = 0; nn < 4; nn++) {
                float g = acc1[nn][reg], u = acc3[nn][reg];
                float h = (g / (1.f + __expf(-g))) * u;
                H[rowoff + nn * 16 + (lane & 15)] = f2bf(h);
            }
        }
    }
}

// ---------------- GEMM2: out[t] += (H * W2) * gate_w  (f32 atomicAdd) ----------------
__global__ __launch_bounds__(256) void k_gemm2(const unsigned short* __restrict__ H,
                                               const void* __restrict__ w2,
                                               const int*  __restrict__ meta,
                                               const int4* __restrict__ tiles,
                                               const int*  __restrict__ pt,
                                               const float* __restrict__ pw,
                                               float* __restrict__ out,
                                               int cbase, int clen)
{
    __shared__ unsigned short As[64 * LDA];
    __shared__ unsigned short Bs[64 * LDA];
    int nt = iclamp(meta[25], 0, MAX_TILES);
    if ((int)blockIdx.x >= nt) return;
    int4 td = tiles[blockIdx.x];
    if (td.x < cbase || td.x >= cbase + clen) return;
    int fl   = meta[26];
    int base = iclamp(td.x, 0, NPAIR-1);
    int e    = iclamp(td.y, 0, E_NUM-1);
    int rows = iclamp(td.z, 1, BM);
    if (base + rows > NPAIR) rows = NPAIR - base;
    int hrows = clen + 64;
    int lbase_r = base - cbase;
    int n0 = blockIdx.y * 64;
    int tid = threadIdx.x, lane = tid & 63, wv = tid >> 6;

    int arow = tid >> 2;
    int acol = (tid & 3) * 16;
    int ar   = arow < rows ? arow : rows - 1;
    int ahr  = iclamp(lbase_r + ar, 0, hrows - 1);
    const unsigned short* aptr = H + (size_t)ahr * F_DIM + acol;

    int bf0 = (tid & 15) * 4;
    int bd0 = ((tid & 127) >> 4) * 8;
    size_t bb = (size_t)e * F_DIM * D_DIM + (size_t)n0 + bd0;   // + (bf0+k0+i)*D

    f32_4 acc[4];
#pragma unroll
    for (int nn = 0; nn < 4; nn++) acc[nn] = 0.f;

    for (int k0 = 0; k0 < F_DIM; k0 += 64) {
        uint4 av0 = *(const uint4*)(aptr + k0);
        uint4 av1 = *(const uint4*)(aptr + k0 + 8);
        *(uint4*)&As[arow * LDA + acol]     = av0;
        *(uint4*)&As[arow * LDA + acol + 8] = av1;
        if (tid < 128) {
            uint4 r0 = load8(w2, bb + (size_t)(bf0 + k0 + 0) * D_DIM, fl);
            uint4 r1 = load8(w2, bb + (size_t)(bf0 + k0 + 1) * D_DIM, fl);
            uint4 r2 = load8(w2, bb + (size_t)(bf0 + k0 + 2) * D_DIM, fl);
            uint4 r3 = load8(w2, bb + (size_t)(bf0 + k0 + 3) * D_DIM, fl);
            const unsigned short* s0 = (const unsigned short*)&r0;
            const unsigned short* s1 = (const unsigned short*)&r1;
            const unsigned short* s2 = (const unsigned short*)&r2;
            const unsigned short* s3 = (const unsigned short*)&r3;
#pragma unroll
            for (int j = 0; j < 8; j++) {
                uint2 pk;
                pk.x = (unsigned)s0[j] | ((unsigned)s1[j] << 16);
                pk.y = (unsigned)s2[j] | ((unsigned)s3[j] << 16);
                *(uint2*)&Bs[(bd0 + j) * LDA + bf0] = pk;   // [d][f]
            }
        }
        __syncthreads();
#pragma unroll
        for (int kk = 0; kk < 2; kk++) {
            int ko = kk * 32 + (lane >> 4) * 8;
            bf16_8 a = *(const bf16_8*)&As[(wv * 16 + (lane & 15)) * LDA + ko];
#pragma unroll
            for (int nn = 0; nn < 4; nn++) {
                bf16_8 b = *(const bf16_8*)&Bs[(nn * 16 + (lane & 15)) * LDA + ko];
                acc[nn] = __builtin_amdgcn_mfma_f32_16x16x32_bf16(a, b, acc[nn], 0, 0, 0);
            }
        }
        __syncthreads();
    }
    // epilogue: f32 atomic accumulate (C/D: col=lane&15, row=(lane>>4)*4+reg)
#pragma unroll
    for (int reg = 0; reg < 4; reg++) {
        int r = wv * 16 + (lane >> 4) * 4 + reg;
        if (r < rows) {
            int idx = iclamp(base + r, 0, NPAIR-1);
            float w = pw[idx];
            int   t = iclamp(pt[idx], 0, T_TOK-1);
#pragma unroll
            for (int nn = 0; nn < 4; nn++) {
                float v = acc[nn][reg] * w;
                atomicAdd(&out[(size_t)t * D_DIM + (size_t)(n0 + nn * 16 + (lane & 15))], v);
            }
        }
    }
}

extern "C" void kernel_launch(void* const* d_in, const int* in_sizes, int n_in,
                              void* d_out, int out_size, void* d_ws, size_t ws_size,
                              hipStream_t stream)
{
    const void* x  = d_in[0];  // [T, D] f32
    const void* wg = d_in[1];  // [D, E] f32
    const void* w1 = d_in[2];  // [E, D, F] f32
    const void* w3 = d_in[3];  // [E, D, F] f32
    const void* w2 = d_in[4];  // [E, F, D] f32
    char* ws = (char*)d_ws;
    float* out = (float*)d_out;   // f32 output (reference returns float32)

    // out is poisoned each call; we accumulate into it -> zero all 32 MB
    k_zero_out<<<8192, 256, 0, stream>>>((uint4*)out);
    if (ws_size < MIN_WS) return;   // diagnostic guard (would show absmax==2.5625)

    int*   meta  = (int*)(ws + META_OFF);
    int4*  tiles = (int4*)(ws + TILE_OFF);
    int*   ridx  = (int*)(ws + RIDX_OFF);
    float* rw    = (float*)(ws + RW_OFF);
    int*   pt    = (int*)(ws + PT_OFF);
    float* pw    = (float*)(ws + PW_OFF);
    unsigned short* H = (unsigned short*)(ws + H_OFF);

    static const int cand[9] = {1, 2, 4, 8, 16, 32, 64, 128, 256};
    int NC = 256;
    for (int i = 0; i < 9; i++) {
        size_t hrows = (size_t)(NPAIR / cand[i]) + 64;
        if (H_OFF + hrows * F_DIM * 2 <= ws_size) { NC = cand[i]; break; }
    }
    int CH = NPAIR / NC;

    k_zero   <<<4, 256, 0, stream>>>(meta);
    k_dtype  <<<1, 64, 0, stream>>>((const unsigned*)x, meta);
    k_router <<<T_TOK / 4, 256, 0, stream>>>(x, wg, meta, ridx, rw);
    k_setup  <<<1, 64, 0, stream>>>(meta, tiles);
    k_scatter<<<T_TOK / 256, 256, 0, stream>>>(ridx, rw, meta, pt, pw);
    for (int c = 0; c < NC; c++) {
        k_gemm1<<<dim3(MAX_TILES, F_DIM / 64), 256, 0, stream>>>(x, w1, w3, meta, tiles, pt, H, c * CH, CH);
        k_gemm2<<<dim3(MAX_TILES, D_DIM / 64), 256, 0, stream>>>(H, w2, meta, tiles, pt, pw, out, c * CH, CH);
    }
}